// Round 18
// baseline (377.331 us; speedup 1.0000x reference)
//
#include <hip/hip_runtime.h>
#include <hip/hip_bf16.h>
#include <math.h>

// Problem constants
#define BB 8
#define CC 192
#define HH 56
#define WW 56
#define NPTS 3136        // H*W
#define OUTC 192
#define KNN 9
#define NTILES 49        // NPTS/64
#define NCH 2            // k2 column chunks
#define NT4 98           // NPTS/32
#define NBLK4 (NT4 * BB) // 784
#define K2BLKS (BB * NCH * NTILES)          // 784
#define K3BLKS ((BB * NPTS / 64) * 6)       // 2352

typedef __bf16 bf16x8 __attribute__((ext_vector_type(8)));
typedef float  f32x16 __attribute__((ext_vector_type(16)));

__device__ __forceinline__ unsigned short f2bf(float f) {
    unsigned u = __float_as_uint(f);
    u += 0x7fffu + ((u >> 16) & 1u);       // RNE
    return (unsigned short)(u >> 16);
}
__device__ __forceinline__ float bf2f(unsigned short h) {
    return __uint_as_float(((unsigned)h) << 16);
}
__device__ __forceinline__ float gelu_f(float z) {
    return 0.5f * z * (1.0f + erff(z * 0.70710678118654752f));
}

// sorted-ascending top-12 insert, u32 keys (dist-high-bits | 9-bit tag)
__device__ __forceinline__ void ins12u32(unsigned (&t)[12], unsigned key) {
    if (key >= t[11]) return;
    t[11] = key;
#pragma unroll
    for (int q = 11; q > 0; --q) {
        const unsigned a = t[q-1], bq = t[q];
        const bool sw = bq < a;
        t[q-1] = sw ? bq : a;
        t[q]   = sw ? a : bq;
    }
}

// sorted-ascending top-12 insert, u64 keys
__device__ __forceinline__ void ins12u(unsigned long long (&t)[12], unsigned long long key) {
    if (key >= t[11]) return;
    t[11] = key;
#pragma unroll
    for (int q = 11; q > 0; --q) {
        const unsigned long long a = t[q-1], bq = t[q];
        const bool sw = bq < a;
        t[q-1] = sw ? bq : a;
        t[q]   = sw ? a : bq;
    }
}

__device__ __forceinline__ void ins9f(float (&d)[9], int (&ix)[9], float nd, int ni) {
    if (!((nd < d[8]) || (nd == d[8] && ni < ix[8]))) return;
    d[8] = nd; ix[8] = ni;
#pragma unroll
    for (int q = 8; q > 0; --q) {
        if ((d[q] < d[q-1]) || (d[q] == d[q-1] && ix[q] < ix[q-1])) {
            float t = d[q]; d[q] = d[q-1]; d[q-1] = t;
            int t2 = ix[q]; ix[q] = ix[q-1]; ix[q-1] = t2;
        }
    }
}

// ---------------------------------------------------------------------------
// K1: transpose (B,C,N)->(B,N,C), L2-normalize rows; emit xn (f32),
//     xh/xl (bf16 hi/lo split of xn), norm, sqv = sum(xn^2) fp32
// ---------------------------------------------------------------------------
__global__ __launch_bounds__(256) void k1_normalize(const float* __restrict__ x,
                                                    float* __restrict__ xn,
                                                    unsigned short* __restrict__ xh,
                                                    unsigned short* __restrict__ xl,
                                                    float* __restrict__ normv,
                                                    float* __restrict__ sqv) {
    const int b  = blockIdx.y;
    const int n0 = blockIdx.x * 64;
    __shared__ float tile[64 * 193];
    __shared__ float red[4][64];
    __shared__ float inv[64];
    const int tid = threadIdx.x;
    const int p   = tid & 63;
    const int cg  = tid >> 6;
    const float* xb = x + (size_t)b * CC * NPTS;

    float acc = 0.f;
#pragma unroll 4
    for (int t = 0; t < 48; ++t) {
        const int c = cg * 48 + t;
        const float v = xb[(size_t)c * NPTS + n0 + p];
        tile[p * 193 + c] = v;
        acc += v * v;
    }
    red[cg][p] = acc;
    __syncthreads();
    if (cg == 0) {
        const float s  = red[0][p] + red[1][p] + red[2][p] + red[3][p];
        float nc = sqrtf(s);
        nc = fmaxf(nc, 1e-12f);
        normv[b * NPTS + n0 + p] = nc;
        const float iv = 1.0f / nc;
        inv[p] = iv;
        sqv[b * NPTS + n0 + p] = s * iv * iv;
    }
    __syncthreads();
    const size_t base = ((size_t)b * NPTS + n0) * CC;
    float* dst = xn + base;
    for (int q = tid; q < 64 * CC / 4; q += 256) {
        const int f   = q * 4;
        const int row = f / CC;
        const int c   = f - row * CC;
        const float iv = inv[row];
        float4 v;
        v.x = tile[row * 193 + c + 0] * iv;
        v.y = tile[row * 193 + c + 1] * iv;
        v.z = tile[row * 193 + c + 2] * iv;
        v.w = tile[row * 193 + c + 3] * iv;
        *(float4*)&dst[f] = v;
        ushort4 hv, lv;
        hv.x = f2bf(v.x); lv.x = f2bf(v.x - bf2f(hv.x));
        hv.y = f2bf(v.y); lv.y = f2bf(v.y - bf2f(hv.y));
        hv.z = f2bf(v.z); lv.z = f2bf(v.z - bf2f(hv.z));
        hv.w = f2bf(v.w); lv.w = f2bf(v.w - bf2f(hv.w));
        *(ushort4*)&xh[base + f] = hv;
        *(ushort4*)&xl[base + f] = lv;
    }
}

// ---------------------------------------------------------------------------
// K23 mega-kernel: k2 (KNN) blocks + k3 (uv GEMM) backfill blocks.
// k2 body (R16): R14 structure with DUAL LDS planes — Ch and Cl staged
// together in one phase (12 loads in flight = 2x MLP), both MFMA phases
// back-to-back: 2 barriers/tile instead of 4. Zero extra registers
// (R15's reg-prefetch spilled to scratch: 813MB WRITE_SIZE).
// LDS 51.2 KB; regs ~196/wave keep 2 waves/SIMD (known floor).
// ---------------------------------------------------------------------------
__global__ __launch_bounds__(256) void k23_mega(const unsigned short* __restrict__ xh,
                                                const unsigned short* __restrict__ xl,
                                                unsigned long long* __restrict__ pd,
                                                const unsigned short* __restrict__ wh,
                                                const unsigned short* __restrict__ wl,
                                                const float* __restrict__ normv,
                                                const float* __restrict__ conv_b,
                                                float* __restrict__ uv) {
    __shared__ __align__(16) char smem[51200];
    const int bid = blockIdx.x;
    const int tid = threadIdx.x;
    const int w    = tid >> 6;
    const int lane = tid & 63;
    const int l31  = lane & 31;
    const int lhi  = lane >> 5;
    const int koffe = lhi * 8;

    if (bid < K2BLKS) {
        // ================= k2 body: transposed-MFMA cosine-KNN ==============
        const int b     = bid & 7;                 // XCD pin
        const int chunk = (bid >> 3) & 1;
        const int r0    = (bid >> 4) * 64;
        const int t0    = chunk ? 25 : 0;
        const int t1    = chunk ? 49 : 25;

        unsigned short* Chs = (unsigned short*)smem;            // [64][200] hi plane
        unsigned short* Cls = (unsigned short*)(smem + 25600);  // [64][200] lo plane
        unsigned long long* cdu = (unsigned long long*)smem;    // alias Chs after loop

        const int wc    = w & 1;         // row half
        const int wr    = w >> 1;        // col half
        const int myrow = wc * 32 + l31;
        const int spnt  = tid >> 2;      // staging point 0..63
        const int sj    = tid & 3;       // staging sub-chunk

        // stationary row fragments (hi+lo)
        const size_t rbase = ((size_t)b * NPTS + (r0 + myrow)) * CC;
        bf16x8 Rh[12], Rl[12];
#pragma unroll
        for (int c = 0; c < 12; ++c) {
            Rh[c] = *(const bf16x8*)(const void*)(xh + rbase + c * 16 + koffe);
            Rl[c] = *(const bf16x8*)(const void*)(xl + rbase + c * 16 + koffe);
        }

        unsigned t12[12];
#pragma unroll
        for (int q = 0; q < 12; ++q) t12[q] = 0xFFFFFFFFu;

        const int cfb = (wr * 32 + l31) * 200 + koffe;

        for (int ct = t0; ct < t1; ++ct) {
            const size_t pb = ((size_t)b * NPTS + ct * 64 + spnt) * CC;
            __syncthreads();   // prev tile's MFMA reads done before overwrite
            // stage BOTH planes (12 loads in flight, then 12 ds_writes)
#pragma unroll
            for (int rep = 0; rep < 6; ++rep) {
                const int j = sj + rep * 4;      // 0..23
                *(uint4*)(void*)&Chs[spnt * 200 + j * 8] =
                    *(const uint4*)(const void*)(xh + pb + j * 8);
            }
#pragma unroll
            for (int rep = 0; rep < 6; ++rep) {
                const int j = sj + rep * 4;
                *(uint4*)(void*)&Cls[spnt * 200 + j * 8] =
                    *(const uint4*)(const void*)(xl + pb + j * 8);
            }
            __syncthreads();   // planes visible

            f32x16 acc;
#pragma unroll
            for (int r = 0; r < 16; ++r) acc[r] = 0.f;

            // phase A: Ch·Rh + Ch·Rl (cols as operand A -> lane axis = row)
#pragma unroll
            for (int c = 0; c < 12; ++c) {
                const bf16x8 cf = *(const bf16x8*)(const void*)&Chs[cfb + c * 16];
                acc = __builtin_amdgcn_mfma_f32_32x32x16_bf16(cf, Rh[c], acc, 0, 0, 0);
                acc = __builtin_amdgcn_mfma_f32_32x32x16_bf16(cf, Rl[c], acc, 0, 0, 0);
            }
            // phase B: Cl·Rh
#pragma unroll
            for (int c = 0; c < 12; ++c) {
                const bf16x8 cl = *(const bf16x8*)(const void*)&Cls[cfb + c * 16];
                acc = __builtin_amdgcn_mfma_f32_32x32x16_bf16(cl, Rh[c], acc, 0, 0, 0);
            }

            // scan 16 candidates in registers
            const unsigned tbase = (unsigned)((ct - t0) << 4);
#pragma unroll
            for (int reg = 0; reg < 16; ++reg) {
                const float d = fmaxf(1.0f - acc[reg], 0.0f);
                const unsigned key = (__float_as_uint(d) & 0xFFFFFE00u) | (tbase | (unsigned)reg);
                ins12u32(t12, key);
            }
        }

        __syncthreads();   // ALIAS SAFETY: MFMA reads done before cdu writes
        // dump per-lane list with col reconstruction: u64 = key<<32 | col
#pragma unroll
        for (int q = 0; q < 12; ++q) {
            const unsigned key = t12[q];
            const int tag = (int)(key & 511u);
            const int reg = tag & 15;
            const int col = (t0 + (tag >> 4)) * 64 + wr * 32 + ((reg & 3) + 8 * (reg >> 2) + 4 * lhi);
            cdu[(((wr * 2 + lhi) * 64) + myrow) * 12 + q] = ((unsigned long long)key << 32) | (unsigned)col;
        }
        __syncthreads();
        // merge 4 lists per row -> top-12, write to pd
        if (tid < 64) {
            unsigned long long t[12];
#pragma unroll
            for (int q = 0; q < 12; ++q) t[q] = cdu[tid * 12 + q];
            for (int s = 1; s < 4; ++s)
#pragma unroll
                for (int q = 0; q < 12; ++q) ins12u(t, cdu[(s * 64 + tid) * 12 + q]);
            const size_t gbase = ((size_t)b * NPTS + r0 + tid) * (NCH * 12) + chunk * 12;
#pragma unroll
            for (int q = 0; q < 12; ++q) pd[gbase + q] = t[q];
        }
    } else {
        // ================= k3 body: MFMA split-bf16 uv GEMM =================
        const int id2 = bid - K2BLKS;
        const int ot  = id2 % 6;
        const int mt  = id2 / 6;
        const int m0  = mt * 64;
        const int o0  = ot * 64;
        const int wr  = w >> 1;
        const int wc  = w & 1;

        const size_t abase = (size_t)(m0 + wr * 32 + l31) * CC;
        bf16x8 Ah[12], Al[12];
#pragma unroll
        for (int c = 0; c < 12; ++c) {
            Ah[c] = *(const bf16x8*)(const void*)(xh + abase + c * 16 + koffe);
            Al[c] = *(const bf16x8*)(const void*)(xl + abase + c * 16 + koffe);
        }
        const int o = o0 + wc * 32 + l31;
        const unsigned short* whr = wh + (size_t)o * CC;
        const unsigned short* wlr = wl + (size_t)o * CC;

        f32x16 acc;
#pragma unroll
        for (int r = 0; r < 16; ++r) acc[r] = 0.f;
#pragma unroll
        for (int c = 0; c < 12; ++c) {
            const bf16x8 bh = *(const bf16x8*)(const void*)(whr + c * 16 + koffe);
            const bf16x8 bl = *(const bf16x8*)(const void*)(wlr + c * 16 + koffe);
            acc = __builtin_amdgcn_mfma_f32_32x32x16_bf16(Ah[c], bh, acc, 0, 0, 0);
            acc = __builtin_amdgcn_mfma_f32_32x32x16_bf16(Al[c], bh, acc, 0, 0, 0);
            acc = __builtin_amdgcn_mfma_f32_32x32x16_bf16(Ah[c], bl, acc, 0, 0, 0);
        }
        const float bias = (o < OUTC) ? conv_b[o] : 0.0f;
#pragma unroll
        for (int reg = 0; reg < 16; ++reg) {
            const int m = m0 + wr * 32 + (reg & 3) + 8 * (reg >> 2) + 4 * lhi;
            uv[(size_t)m * (2 * OUTC) + o] = acc[reg] * normv[m] + bias;
        }
    }
}

// ---------------------------------------------------------------------------
// K2b: merge NCH chunk lists -> top-12; AMBIGUITY-GATED fp32 re-rank.
// ---------------------------------------------------------------------------
__global__ __launch_bounds__(128) void k2b_merge(const float* __restrict__ xn,
                                                 const float* __restrict__ sqv,
                                                 const unsigned long long* __restrict__ pd,
                                                 int* __restrict__ idxout) {
    const int b  = blockIdx.x;                  // XCD pin
    const int r0 = blockIdx.y * 32;
    __shared__ __align__(16) float xr_s[32][196];
    __shared__ int   ci[32][12];
    __shared__ float dd[32][13];
    __shared__ int   need[32];
    const int tid = threadIdx.x;
    const float* xb = xn + (size_t)b * NPTS * CC;

    for (int q = tid; q < 32 * 48; q += 128) {
        const int row = q / 48, c4 = q - row * 48;
        *(float4*)&xr_s[row][c4 * 4] = *(const float4*)&xb[(size_t)(r0 + row) * CC + c4 * 4];
    }
    if (tid < 32) {
        const size_t base = ((size_t)b * NPTS + r0 + tid) * (NCH * 12);
        unsigned long long t[12];
#pragma unroll
        for (int q = 0; q < 12; ++q) t[q] = pd[base + q];
        for (int s = 1; s < NCH; ++s)
#pragma unroll
            for (int q = 0; q < 12; ++q) ins12u(t, pd[base + s * 12 + q]);
#pragma unroll
        for (int q = 0; q < 12; ++q) ci[tid][q] = (int)(t[q] & 0xFFFFFFFFull);
        const float d9  = __uint_as_float((unsigned)(t[8] >> 32) & 0xFFFFFE00u);
        const float d10 = __uint_as_float((unsigned)(t[9] >> 32) & 0xFFFFFE00u);
        need[tid] = (d10 - d9) < 3e-4f ? 1 : 0;
    }
    __syncthreads();
    {
        const int p = tid >> 2;
        const int s = tid & 3;
        if (need[p]) {
            const float sqn = sqv[(size_t)b * NPTS + r0 + p];
#pragma unroll
            for (int t3 = 0; t3 < 3; ++t3) {
                const int cs2 = s + t3 * 4;
                const int m   = ci[p][cs2];
                const float* xm = xb + (size_t)m * CC;
                float4 a4 = make_float4(0.f, 0.f, 0.f, 0.f);
#pragma unroll 8
                for (int c4 = 0; c4 < 48; ++c4) {
                    const float4 xv = *(const float4*)&xm[c4 * 4];
                    const float4 rv = *(const float4*)&xr_s[p][c4 * 4];
                    a4.x += rv.x * xv.x;
                    a4.y += rv.y * xv.y;
                    a4.z += rv.z * xv.z;
                    a4.w += rv.w * xv.w;
                }
                const float dot = (a4.x + a4.y) + (a4.z + a4.w);
                dd[p][cs2] = sqn + sqv[(size_t)b * NPTS + m] - 2.0f * dot;
            }
        }
    }
    __syncthreads();
    if (tid < 32) {
        int* orow = &idxout[((size_t)b * NPTS + r0 + tid) * KNN];
        if (need[tid]) {
            float fd[9]; int fi[9];
#pragma unroll
            for (int q = 0; q < 9; ++q) { fd[q] = 3.4e38f; fi[q] = 0x7fffffff; }
#pragma unroll
            for (int cs2 = 0; cs2 < 12; ++cs2)
                ins9f(fd, fi, dd[tid][cs2], ci[tid][cs2]);
#pragma unroll
            for (int q = 0; q < 9; ++q) orow[q] = fi[q];
        } else {
#pragma unroll
            for (int q = 0; q < 9; ++q) orow[q] = ci[tid][q];
        }
    }
}

// ---------------------------------------------------------------------------
// K3a: wh/wl = bf16 hi/lo split of [W1-W2 ; W2]
// ---------------------------------------------------------------------------
__global__ __launch_bounds__(256) void k3a_wcat(const float* __restrict__ cw,
                                               unsigned short* __restrict__ wh,
                                               unsigned short* __restrict__ wl) {
    const int i = blockIdx.x * 256 + threadIdx.x;
    if (i < 2 * OUTC * CC) {
        const int r = i / CC, c = i - r * CC;
        float val;
        if (r < OUTC) val = cw[r * (2 * CC) + c] - cw[r * (2 * CC) + CC + c];
        else          val = cw[(r - OUTC) * (2 * CC) + CC + c];
        const unsigned short h = f2bf(val);
        wh[i] = h;
        wl[i] = f2bf(val - bf2f(h));
    }
}

// ---------------------------------------------------------------------------
// K4_fused: one pass over the 9-neighbor gather:
//   amax[n][o] = u[n][o] + max_k v[idx][o],  amin = u + min_k v
//   per-block BN partials: S = sum_k (u+v), Q = sum_k (u+v)^2
// ---------------------------------------------------------------------------
__global__ __launch_bounds__(256) void k4_fused(const float* __restrict__ uv,
                                                const int* __restrict__ idxb,
                                                float* __restrict__ amax,
                                                float* __restrict__ amin,
                                                float* __restrict__ partials) {
    const int flat = blockIdx.x;
    const int b    = flat & 7;           // XCD pin
    const int tile = flat >> 3;
    const int tid  = threadIdx.x;
    const int p    = tid >> 3;
    const int g    = tid & 7;
    const int n    = tile * 32 + p;
    const size_t base = (size_t)b * NPTS;
    __shared__ float red[256 * 25];

    float sv[24], sv2[24], vmx[24], vmn[24];
#pragma unroll
    for (int c = 0; c < 24; ++c) { sv[c] = 0.f; sv2[c] = 0.f; vmx[c] = -3.4e38f; vmn[c] = 3.4e38f; }

    const int* ix = &idxb[(base + n) * KNN];
#pragma unroll
    for (int k = 0; k < KNN; ++k) {
        const int m = ix[k];
        const float* vr = &uv[(base + m) * (2 * OUTC) + OUTC + g * 24];
#pragma unroll
        for (int c4 = 0; c4 < 6; ++c4) {
            const float4 v = *(const float4*)&vr[c4 * 4];
            const int c = c4 * 4;
            sv[c+0] += v.x; sv2[c+0] += v.x*v.x; vmx[c+0] = fmaxf(vmx[c+0], v.x); vmn[c+0] = fminf(vmn[c+0], v.x);
            sv[c+1] += v.y; sv2[c+1] += v.y*v.y; vmx[c+1] = fmaxf(vmx[c+1], v.y); vmn[c+1] = fminf(vmn[c+1], v.y);
            sv[c+2] += v.z; sv2[c+2] += v.z*v.z; vmx[c+2] = fmaxf(vmx[c+2], v.z); vmn[c+2] = fminf(vmn[c+2], v.z);
            sv[c+3] += v.w; sv2[c+3] += v.w*v.w; vmx[c+3] = fmaxf(vmx[c+3], v.w); vmn[c+3] = fminf(vmn[c+3], v.w);
        }
    }
    const float* ur = &uv[(base + n) * (2 * OUTC) + g * 24];
    float S[24], Q[24];
    float* am = &amax[(base + n) * OUTC + g * 24];
    float* an = &amin[(base + n) * OUTC + g * 24];
#pragma unroll
    for (int c4 = 0; c4 < 6; ++c4) {
        const float4 u4 = *(const float4*)&ur[c4 * 4];
        const int c = c4 * 4;
        float4 mx, mn;
        mx.x = u4.x + vmx[c+0]; mn.x = u4.x + vmn[c+0];
        mx.y = u4.y + vmx[c+1]; mn.y = u4.y + vmn[c+1];
        mx.z = u4.z + vmx[c+2]; mn.z = u4.z + vmn[c+2];
        mx.w = u4.w + vmx[c+3]; mn.w = u4.w + vmn[c+3];
        *(float4*)&am[c4 * 4] = mx;
        *(float4*)&an[c4 * 4] = mn;
        S[c+0] = 9.f*u4.x + sv[c+0];  Q[c+0] = u4.x*(9.f*u4.x + 2.f*sv[c+0]) + sv2[c+0];
        S[c+1] = 9.f*u4.y + sv[c+1];  Q[c+1] = u4.y*(9.f*u4.y + 2.f*sv[c+1]) + sv2[c+1];
        S[c+2] = 9.f*u4.z + sv[c+2];  Q[c+2] = u4.z*(9.f*u4.z + 2.f*sv[c+2]) + sv2[c+2];
        S[c+3] = 9.f*u4.w + sv[c+3];  Q[c+3] = u4.w*(9.f*u4.w + 2.f*sv[c+3]) + sv2[c+3];
    }
#pragma unroll
    for (int c = 0; c < 24; ++c) red[tid * 25 + c] = S[c];
    __syncthreads();
    float accS = 0.f;
    if (tid < OUTC) {
        const int go = tid / 24, co = tid - go * 24;
        for (int pp = 0; pp < 32; ++pp) accS += red[(pp * 8 + go) * 25 + co];
    }
    __syncthreads();
#pragma unroll
    for (int c = 0; c < 24; ++c) red[tid * 25 + c] = Q[c];
    __syncthreads();
    if (tid < OUTC) {
        const int go = tid / 24, co = tid - go * 24;
        float accQ = 0.f;
        for (int pp = 0; pp < 32; ++pp) accQ += red[(pp * 8 + go) * 25 + co];
        partials[(size_t)flat * (2 * OUTC) + tid]        = accS;
        partials[(size_t)flat * (2 * OUTC) + OUTC + tid] = accQ;
    }
}

// ---------------------------------------------------------------------------
// K4b: parallel deterministic reduce: one block per channel.
// ---------------------------------------------------------------------------
__global__ __launch_bounds__(256) void k4b_finalize(const float* __restrict__ partials,
                                                    const float* __restrict__ gamma,
                                                    const float* __restrict__ beta,
                                                    float* __restrict__ scsh) {
    const int o   = blockIdx.x;
    const int tid = threadIdx.x;
    __shared__ float sS[256], sQ[256];
    float S = 0.f, Q = 0.f;
    for (int blk = tid; blk < NBLK4; blk += 256) {
        S += partials[(size_t)blk * (2 * OUTC) + o];
        Q += partials[(size_t)blk * (2 * OUTC) + OUTC + o];
    }
    sS[tid] = S; sQ[tid] = Q;
    __syncthreads();
    for (int s = 128; s > 0; s >>= 1) {
        if (tid < s) { sS[tid] += sS[tid + s]; sQ[tid] += sQ[tid + s]; }
        __syncthreads();
    }
    if (tid == 0) {
        const float cnt  = (float)BB * (float)NPTS * (float)KNN;
        const float mean = sS[0] / cnt;
        float var = fmaxf(sQ[0] / cnt - mean * mean, 0.0f);
        const float scale = gamma[o] * rsqrtf(var + 1e-5f);
        scsh[o]        = scale;
        scsh[OUTC + o] = beta[o] - mean * scale;
    }
}

// ---------------------------------------------------------------------------
// K5: out[b][o][n] = max(gelu(amax*sc+sh), gelu(amin*sc+sh))  (gelu unimodal)
// ---------------------------------------------------------------------------
__global__ __launch_bounds__(256) void k5_out(const float* __restrict__ amax,
                                              const float* __restrict__ amin,
                                              const float* __restrict__ scsh,
                                              float* __restrict__ out) {
    const int b  = blockIdx.y;
    const int n0 = blockIdx.x * 64;
    __shared__ float zb[64 * 193];
    __shared__ float ssc[OUTC];
    __shared__ float ssh[OUTC];
    const int tid = threadIdx.x;
    for (int q = tid; q < OUTC; q += 256) {
        ssc[q] = scsh[q];
        ssh[q] = scsh[OUTC + q];
    }
    __syncthreads();
    const int p  = tid >> 2;
    const int og = tid & 3;
    const int n  = n0 + p;
    const size_t rb = ((size_t)b * NPTS + n) * OUTC + og * 48;
#pragma unroll
    for (int t4 = 0; t4 < 12; ++t4) {
        const float4 ax = *(const float4*)&amax[rb + t4 * 4];
        const float4 an = *(const float4*)&amin[rb + t4 * 4];
        const int ob = og * 48 + t4 * 4;
        float z1, z2;
        z1 = ax.x * ssc[ob+0] + ssh[ob+0]; z2 = an.x * ssc[ob+0] + ssh[ob+0];
        zb[p * 193 + ob + 0] = fmaxf(gelu_f(z1), gelu_f(z2));
        z1 = ax.y * ssc[ob+1] + ssh[ob+1]; z2 = an.y * ssc[ob+1] + ssh[ob+1];
        zb[p * 193 + ob + 1] = fmaxf(gelu_f(z1), gelu_f(z2));
        z1 = ax.z * ssc[ob+2] + ssh[ob+2]; z2 = an.z * ssc[ob+2] + ssh[ob+2];
        zb[p * 193 + ob + 2] = fmaxf(gelu_f(z1), gelu_f(z2));
        z1 = ax.w * ssc[ob+3] + ssh[ob+3]; z2 = an.w * ssc[ob+3] + ssh[ob+3];
        zb[p * 193 + ob + 3] = fmaxf(gelu_f(z1), gelu_f(z2));
    }
    __syncthreads();
    float* ob2 = out + (size_t)b * OUTC * NPTS;
    for (int q = tid; q < 64 * OUTC; q += 256) {
        const int o  = q >> 6;
        const int pp = q & 63;
        ob2[(size_t)o * NPTS + n0 + pp] = zb[pp * 193 + o];
    }
}

// ---------------------------------------------------------------------------
extern "C" void kernel_launch(void* const* d_in, const int* in_sizes, int n_in,
                              void* d_out, int out_size, void* d_ws, size_t ws_size,
                              hipStream_t stream) {
    const float* x        = (const float*)d_in[0];
    const float* conv_w   = (const float*)d_in[1];
    const float* conv_b   = (const float*)d_in[2];
    const float* bn_gamma = (const float*)d_in[3];
    const float* bn_beta  = (const float*)d_in[4];
    float* out = (float*)d_out;

    // workspace layout
    float* ws = (float*)d_ws;
    const size_t SZ_XN = (size_t)BB * NPTS * CC;     // 4,816,896
    const size_t SZ_NV = (size_t)BB * NPTS;          // 25,088
    const size_t SZ_A  = (size_t)BB * NPTS * OUTC;   // 4,816,896

    int*   idxb        = (int*)ws;                                  // 225,792 i32
    unsigned short* wh = (unsigned short*)(idxb + (size_t)BB * NPTS * KNN);  // 73,728 u16
    unsigned short* wl = wh + (size_t)(2 * OUTC) * CC;                       // 73,728 u16
    float* uv       = (float*)(wl + (size_t)(2 * OUTC) * CC);       // 9,633,792 f
    float* partials = uv + (size_t)BB * NPTS * (2 * OUTC);          // NBLK4*384 f
    float* scsh     = partials + (size_t)NBLK4 * (2 * OUTC);        // 384 f
    float* normv    = scsh + 2 * OUTC;                              // 25,088 f
    float* sqv      = normv + SZ_NV;                                // 25,088 f
    float* xn       = sqv + SZ_NV;                                  // 4,816,896 f
    unsigned short* xh = (unsigned short*)(xn + SZ_XN);             // 4,816,896 u16
    unsigned short* xl = xh + SZ_XN;                                // 4,816,896 u16
    // pd DEDICATED (k3 writes uv concurrently in the mega dispatch):
    unsigned long long* pd = (unsigned long long*)(xl + SZ_XN);     // B*N*NCH*12 u64 = 4.8 MB
    // aliases (non-overlapping lifetimes):
    float* amax = xn;                                    // xn dead after k2b
    float* amin = xn + SZ_A;                             // spans dead xh/xl region

    k1_normalize<<<dim3(NTILES, BB), 256, 0, stream>>>(x, xn, xh, xl, normv, sqv);
    k3a_wcat<<<(2 * OUTC * CC + 255) / 256, 256, 0, stream>>>(conv_w, wh, wl);
    k23_mega<<<K2BLKS + K3BLKS, 256, 0, stream>>>(xh, xl, pd, wh, wl, normv, conv_b, uv);
    k2b_merge<<<dim3(BB, NT4), 128, 0, stream>>>(xn, sqv, pd, idxb);
    k4_fused<<<NBLK4, 256, 0, stream>>>(uv, idxb, amax, amin, partials);
    k4b_finalize<<<OUTC, 256, 0, stream>>>(partials, bn_gamma, bn_beta, scsh);
    k5_out<<<dim3(NTILES, BB), 256, 0, stream>>>(amax, amin, scsh, out);
}

// Round 19
// 349.708 us; speedup vs baseline: 1.0790x; 1.0790x over previous
//
#include <hip/hip_runtime.h>
#include <hip/hip_bf16.h>
#include <math.h>

// Problem constants
#define BB 8
#define CC 192
#define HH 56
#define WW 56
#define NPTS 3136        // H*W
#define OUTC 192
#define KNN 9
#define NTILES 49        // NPTS/64
#define NCH 2            // k2 column chunks
#define NT4 98           // NPTS/32
#define NBLK4 (NT4 * BB) // 784
#define K2BLKS (BB * NCH * NTILES)          // 784
#define K3BLKS ((BB * NPTS / 64) * 6)       // 2352

typedef __bf16 bf16x8 __attribute__((ext_vector_type(8)));
typedef float  f32x16 __attribute__((ext_vector_type(16)));
typedef int    i32x4  __attribute__((ext_vector_type(4)));

__device__ __forceinline__ unsigned short f2bf(float f) {
    unsigned u = __float_as_uint(f);
    u += 0x7fffu + ((u >> 16) & 1u);       // RNE
    return (unsigned short)(u >> 16);
}
__device__ __forceinline__ float bf2f(unsigned short h) {
    return __uint_as_float(((unsigned)h) << 16);
}
__device__ __forceinline__ float gelu_f(float z) {
    return 0.5f * z * (1.0f + erff(z * 0.70710678118654752f));
}

// sorted-ascending top-12 insert, u32 keys (dist-high-bits | 9-bit tag)
__device__ __forceinline__ void ins12u32(unsigned (&t)[12], unsigned key) {
    if (key >= t[11]) return;
    t[11] = key;
#pragma unroll
    for (int q = 11; q > 0; --q) {
        const unsigned a = t[q-1], bq = t[q];
        const bool sw = bq < a;
        t[q-1] = sw ? bq : a;
        t[q]   = sw ? a : bq;
    }
}

// sorted-ascending top-12 insert, u64 keys
__device__ __forceinline__ void ins12u(unsigned long long (&t)[12], unsigned long long key) {
    if (key >= t[11]) return;
    t[11] = key;
#pragma unroll
    for (int q = 11; q > 0; --q) {
        const unsigned long long a = t[q-1], bq = t[q];
        const bool sw = bq < a;
        t[q-1] = sw ? bq : a;
        t[q]   = sw ? a : bq;
    }
}

__device__ __forceinline__ void ins9f(float (&d)[9], int (&ix)[9], float nd, int ni) {
    if (!((nd < d[8]) || (nd == d[8] && ni < ix[8]))) return;
    d[8] = nd; ix[8] = ni;
#pragma unroll
    for (int q = 8; q > 0; --q) {
        if ((d[q] < d[q-1]) || (d[q] == d[q-1] && ix[q] < ix[q-1])) {
            float t = d[q]; d[q] = d[q-1]; d[q-1] = t;
            int t2 = ix[q]; ix[q] = ix[q-1]; ix[q-1] = t2;
        }
    }
}

// ---------------------------------------------------------------------------
// K1: transpose (B,C,N)->(B,N,C), L2-normalize rows; emit xn (f32),
//     xh/xl (bf16 hi/lo split of xn), norm, sqv = sum(xn^2) fp32
// ---------------------------------------------------------------------------
__global__ __launch_bounds__(256) void k1_normalize(const float* __restrict__ x,
                                                    float* __restrict__ xn,
                                                    unsigned short* __restrict__ xh,
                                                    unsigned short* __restrict__ xl,
                                                    float* __restrict__ normv,
                                                    float* __restrict__ sqv) {
    const int b  = blockIdx.y;
    const int n0 = blockIdx.x * 64;
    __shared__ float tile[64 * 193];
    __shared__ float red[4][64];
    __shared__ float inv[64];
    const int tid = threadIdx.x;
    const int p   = tid & 63;
    const int cg  = tid >> 6;
    const float* xb = x + (size_t)b * CC * NPTS;

    float acc = 0.f;
#pragma unroll 4
    for (int t = 0; t < 48; ++t) {
        const int c = cg * 48 + t;
        const float v = xb[(size_t)c * NPTS + n0 + p];
        tile[p * 193 + c] = v;
        acc += v * v;
    }
    red[cg][p] = acc;
    __syncthreads();
    if (cg == 0) {
        const float s  = red[0][p] + red[1][p] + red[2][p] + red[3][p];
        float nc = sqrtf(s);
        nc = fmaxf(nc, 1e-12f);
        normv[b * NPTS + n0 + p] = nc;
        const float iv = 1.0f / nc;
        inv[p] = iv;
        sqv[b * NPTS + n0 + p] = s * iv * iv;
    }
    __syncthreads();
    const size_t base = ((size_t)b * NPTS + n0) * CC;
    float* dst = xn + base;
    for (int q = tid; q < 64 * CC / 4; q += 256) {
        const int f   = q * 4;
        const int row = f / CC;
        const int c   = f - row * CC;
        const float iv = inv[row];
        float4 v;
        v.x = tile[row * 193 + c + 0] * iv;
        v.y = tile[row * 193 + c + 1] * iv;
        v.z = tile[row * 193 + c + 2] * iv;
        v.w = tile[row * 193 + c + 3] * iv;
        *(float4*)&dst[f] = v;
        ushort4 hv, lv;
        hv.x = f2bf(v.x); lv.x = f2bf(v.x - bf2f(hv.x));
        hv.y = f2bf(v.y); lv.y = f2bf(v.y - bf2f(hv.y));
        hv.z = f2bf(v.z); lv.z = f2bf(v.z - bf2f(hv.z));
        hv.w = f2bf(v.w); lv.w = f2bf(v.w - bf2f(hv.w));
        *(ushort4*)&xh[base + f] = hv;
        *(ushort4*)&xl[base + f] = lv;
    }
}

// ---------------------------------------------------------------------------
// K23 mega-kernel: dispatch-level fusion of k2 (KNN, latency-bound) and k3
// (uv GEMM, independent of k2). k3 blocks backfill k2's idle wave slots.
// k2 body: K-split residency (R13/R14 best-measured config): k0-half row
// frags in regs, k1-half in persistent LDS plane read via volatile loads.
// ---------------------------------------------------------------------------
__global__ __launch_bounds__(256, 3) void k23_mega(const unsigned short* __restrict__ xh,
                                                   const unsigned short* __restrict__ xl,
                                                   unsigned long long* __restrict__ pd,
                                                   const unsigned short* __restrict__ wh,
                                                   const unsigned short* __restrict__ wl,
                                                   const float* __restrict__ normv,
                                                   const float* __restrict__ conv_b,
                                                   float* __restrict__ uv) {
    __shared__ __align__(16) char smem[51200];
    const int bid = blockIdx.x;
    const int tid = threadIdx.x;
    const int w    = tid >> 6;
    const int lane = tid & 63;
    const int l31  = lane & 31;
    const int lhi  = lane >> 5;
    const int koffe = lhi * 8;

    if (bid < K2BLKS) {
        // ================= k2 body: transposed-MFMA cosine-KNN ==============
        const int b     = bid & 7;                 // XCD pin
        const int chunk = (bid >> 3) & 1;
        const int r0    = (bid >> 4) * 64;
        const int t0    = chunk ? 25 : 0;
        const int t1    = chunk ? 49 : 25;

        unsigned short* Cs  = (unsigned short*)smem;            // [64][200]
        unsigned short* Rk1 = (unsigned short*)(smem + 25600);  // [64][200]: k1-hi, k1-lo at +96
        unsigned long long* cdu = (unsigned long long*)smem;    // alias Cs after loop

        const int wc   = w & 1;          // row half
        const int wr   = w >> 1;         // col half
        const int myrow = wc * 32 + l31;
        const int spnt = tid >> 2;
        const int sj   = tid & 3;

        const size_t rbase = ((size_t)b * NPTS + (r0 + myrow)) * CC;
        bf16x8 Rh0[6], Rl0[6];
#pragma unroll
        for (int c = 0; c < 6; ++c) {
            Rh0[c] = *(const bf16x8*)(const void*)(xh + rbase + c * 16 + koffe);
            Rl0[c] = *(const bf16x8*)(const void*)(xl + rbase + c * 16 + koffe);
        }

        {
            const size_t pb = ((size_t)b * NPTS + r0 + spnt) * CC + 96;
#pragma unroll
            for (int rep = 0; rep < 3; ++rep) {
                const int j = sj + rep * 4;
                *(uint4*)(void*)&Rk1[spnt * 200 + j * 8] =
                    *(const uint4*)(const void*)(xh + pb + j * 8);
            }
#pragma unroll
            for (int rep = 0; rep < 3; ++rep) {
                const int j = sj + rep * 4;
                *(uint4*)(void*)&Rk1[spnt * 200 + 96 + j * 8] =
                    *(const uint4*)(const void*)(xl + pb + j * 8);
            }
        }

        unsigned t12[12];
#pragma unroll
        for (int q = 0; q < 12; ++q) t12[q] = 0xFFFFFFFFu;

        const int cfb = (wr * 32 + l31) * 200 + koffe;
        const int rlb = myrow * 200 + koffe;

        for (int ct = t0; ct < t1; ++ct) {
            const int c0 = ct * 64;
            __syncthreads();
            {
                const size_t pb = ((size_t)b * NPTS + c0 + spnt) * CC;
#pragma unroll
                for (int rep = 0; rep < 6; ++rep) {
                    const int j = sj + rep * 4;
                    *(uint4*)(void*)&Cs[spnt * 200 + j * 8] =
                        *(const uint4*)(const void*)(xh + pb + j * 8);
                }
            }
            __syncthreads();

            f32x16 acc;
#pragma unroll
            for (int r = 0; r < 16; ++r) acc[r] = 0.f;

            // phase A1: k0 — Ch·Rh0 + Ch·Rl0
#pragma unroll
            for (int c = 0; c < 6; ++c) {
                const bf16x8 cf = *(const bf16x8*)(const void*)&Cs[cfb + c * 16];
                acc = __builtin_amdgcn_mfma_f32_32x32x16_bf16(cf, Rh0[c], acc, 0, 0, 0);
                acc = __builtin_amdgcn_mfma_f32_32x32x16_bf16(cf, Rl0[c], acc, 0, 0, 0);
            }
            // phase A2: k1 — Ch·Rh1 + Ch·Rl1 (volatile LDS frags: no LICM)
#pragma unroll
            for (int c = 0; c < 6; ++c) {
                const bf16x8 cf = *(const bf16x8*)(const void*)&Cs[cfb + (6 + c) * 16];
                const i32x4 th = *(const volatile i32x4*)(const volatile void*)&Rk1[rlb + c * 16];
                const i32x4 tl = *(const volatile i32x4*)(const volatile void*)&Rk1[rlb + 96 + c * 16];
                acc = __builtin_amdgcn_mfma_f32_32x32x16_bf16(cf, __builtin_bit_cast(bf16x8, th), acc, 0, 0, 0);
                acc = __builtin_amdgcn_mfma_f32_32x32x16_bf16(cf, __builtin_bit_cast(bf16x8, tl), acc, 0, 0, 0);
            }
            __syncthreads();
            {
                const size_t pb = ((size_t)b * NPTS + c0 + spnt) * CC;
#pragma unroll
                for (int rep = 0; rep < 6; ++rep) {
                    const int j = sj + rep * 4;
                    *(uint4*)(void*)&Cs[spnt * 200 + j * 8] =
                        *(const uint4*)(const void*)(xl + pb + j * 8);
                }
            }
            __syncthreads();
            // phase B1: k0 — Cl·Rh0
#pragma unroll
            for (int c = 0; c < 6; ++c) {
                const bf16x8 cl = *(const bf16x8*)(const void*)&Cs[cfb + c * 16];
                acc = __builtin_amdgcn_mfma_f32_32x32x16_bf16(cl, Rh0[c], acc, 0, 0, 0);
            }
            // phase B2: k1 — Cl·Rh1
#pragma unroll
            for (int c = 0; c < 6; ++c) {
                const bf16x8 cl = *(const bf16x8*)(const void*)&Cs[cfb + (6 + c) * 16];
                const i32x4 th = *(const volatile i32x4*)(const volatile void*)&Rk1[rlb + c * 16];
                acc = __builtin_amdgcn_mfma_f32_32x32x16_bf16(cl, __builtin_bit_cast(bf16x8, th), acc, 0, 0, 0);
            }

            const unsigned tbase = (unsigned)((ct - t0) << 4);
#pragma unroll
            for (int reg = 0; reg < 16; ++reg) {
                const float d = fmaxf(1.0f - acc[reg], 0.0f);
                const unsigned key = (__float_as_uint(d) & 0xFFFFFE00u) | (tbase | (unsigned)reg);
                ins12u32(t12, key);
            }
        }

        __syncthreads();   // ALIAS SAFETY before cdu writes
#pragma unroll
        for (int q = 0; q < 12; ++q) {
            const unsigned key = t12[q];
            const int tag = (int)(key & 511u);
            const int reg = tag & 15;
            const int col = (t0 + (tag >> 4)) * 64 + wr * 32 + ((reg & 3) + 8 * (reg >> 2) + 4 * lhi);
            cdu[(((wr * 2 + lhi) * 64) + myrow) * 12 + q] = ((unsigned long long)key << 32) | (unsigned)col;
        }
        __syncthreads();
        if (tid < 64) {
            unsigned long long t[12];
#pragma unroll
            for (int q = 0; q < 12; ++q) t[q] = cdu[tid * 12 + q];
            for (int s = 1; s < 4; ++s)
#pragma unroll
                for (int q = 0; q < 12; ++q) ins12u(t, cdu[(s * 64 + tid) * 12 + q]);
            const size_t gbase = ((size_t)b * NPTS + r0 + tid) * (NCH * 12) + chunk * 12;
#pragma unroll
            for (int q = 0; q < 12; ++q) pd[gbase + q] = t[q];
        }
    } else {
        // ================= k3 body: MFMA split-bf16 uv GEMM =================
        const int id2 = bid - K2BLKS;
        const int ot  = id2 % 6;           // o-tile fast: neighbors share A-rows
        const int mt  = id2 / 6;           // 0..391
        const int m0  = mt * 64;
        const int o0  = ot * 64;
        const int wr  = w >> 1;            // m half
        const int wc  = w & 1;             // o half

        const size_t abase = (size_t)(m0 + wr * 32 + l31) * CC;
        bf16x8 Ah[12], Al[12];
#pragma unroll
        for (int c = 0; c < 12; ++c) {
            Ah[c] = *(const bf16x8*)(const void*)(xh + abase + c * 16 + koffe);
            Al[c] = *(const bf16x8*)(const void*)(xl + abase + c * 16 + koffe);
        }
        const int o = o0 + wc * 32 + l31;
        const unsigned short* whr = wh + (size_t)o * CC;
        const unsigned short* wlr = wl + (size_t)o * CC;

        f32x16 acc;
#pragma unroll
        for (int r = 0; r < 16; ++r) acc[r] = 0.f;
#pragma unroll
        for (int c = 0; c < 12; ++c) {
            const bf16x8 bh = *(const bf16x8*)(const void*)(whr + c * 16 + koffe);
            const bf16x8 bl = *(const bf16x8*)(const void*)(wlr + c * 16 + koffe);
            acc = __builtin_amdgcn_mfma_f32_32x32x16_bf16(Ah[c], bh, acc, 0, 0, 0);
            acc = __builtin_amdgcn_mfma_f32_32x32x16_bf16(Al[c], bh, acc, 0, 0, 0);
            acc = __builtin_amdgcn_mfma_f32_32x32x16_bf16(Ah[c], bl, acc, 0, 0, 0);
        }
        const float bias = (o < OUTC) ? conv_b[o] : 0.0f;
#pragma unroll
        for (int reg = 0; reg < 16; ++reg) {
            const int m = m0 + wr * 32 + (reg & 3) + 8 * (reg >> 2) + 4 * lhi;
            uv[(size_t)m * (2 * OUTC) + o] = acc[reg] * normv[m] + bias;
        }
    }
}

// ---------------------------------------------------------------------------
// K2b: merge NCH chunk lists -> top-12; AMBIGUITY-GATED fp32 re-rank.
// ---------------------------------------------------------------------------
__global__ __launch_bounds__(128) void k2b_merge(const float* __restrict__ xn,
                                                 const float* __restrict__ sqv,
                                                 const unsigned long long* __restrict__ pd,
                                                 int* __restrict__ idxout) {
    const int b  = blockIdx.x;                  // XCD pin
    const int r0 = blockIdx.y * 32;
    __shared__ __align__(16) float xr_s[32][196];
    __shared__ int   ci[32][12];
    __shared__ float dd[32][13];
    __shared__ int   need[32];
    const int tid = threadIdx.x;
    const float* xb = xn + (size_t)b * NPTS * CC;

    for (int q = tid; q < 32 * 48; q += 128) {
        const int row = q / 48, c4 = q - row * 48;
        *(float4*)&xr_s[row][c4 * 4] = *(const float4*)&xb[(size_t)(r0 + row) * CC + c4 * 4];
    }
    if (tid < 32) {
        const size_t base = ((size_t)b * NPTS + r0 + tid) * (NCH * 12);
        unsigned long long t[12];
#pragma unroll
        for (int q = 0; q < 12; ++q) t[q] = pd[base + q];
        for (int s = 1; s < NCH; ++s)
#pragma unroll
            for (int q = 0; q < 12; ++q) ins12u(t, pd[base + s * 12 + q]);
#pragma unroll
        for (int q = 0; q < 12; ++q) ci[tid][q] = (int)(t[q] & 0xFFFFFFFFull);
        const float d9  = __uint_as_float((unsigned)(t[8] >> 32) & 0xFFFFFE00u);
        const float d10 = __uint_as_float((unsigned)(t[9] >> 32) & 0xFFFFFE00u);
        need[tid] = (d10 - d9) < 3e-4f ? 1 : 0;
    }
    __syncthreads();
    {
        const int p = tid >> 2;
        const int s = tid & 3;
        if (need[p]) {
            const float sqn = sqv[(size_t)b * NPTS + r0 + p];
#pragma unroll
            for (int t3 = 0; t3 < 3; ++t3) {
                const int cs2 = s + t3 * 4;
                const int m   = ci[p][cs2];
                const float* xm = xb + (size_t)m * CC;
                float4 a4 = make_float4(0.f, 0.f, 0.f, 0.f);
#pragma unroll 8
                for (int c4 = 0; c4 < 48; ++c4) {
                    const float4 xv = *(const float4*)&xm[c4 * 4];
                    const float4 rv = *(const float4*)&xr_s[p][c4 * 4];
                    a4.x += rv.x * xv.x;
                    a4.y += rv.y * xv.y;
                    a4.z += rv.z * xv.z;
                    a4.w += rv.w * xv.w;
                }
                const float dot = (a4.x + a4.y) + (a4.z + a4.w);
                dd[p][cs2] = sqn + sqv[(size_t)b * NPTS + m] - 2.0f * dot;
            }
        }
    }
    __syncthreads();
    if (tid < 32) {
        int* orow = &idxout[((size_t)b * NPTS + r0 + tid) * KNN];
        if (need[tid]) {
            float fd[9]; int fi[9];
#pragma unroll
            for (int q = 0; q < 9; ++q) { fd[q] = 3.4e38f; fi[q] = 0x7fffffff; }
#pragma unroll
            for (int cs2 = 0; cs2 < 12; ++cs2)
                ins9f(fd, fi, dd[tid][cs2], ci[tid][cs2]);
#pragma unroll
            for (int q = 0; q < 9; ++q) orow[q] = fi[q];
        } else {
#pragma unroll
            for (int q = 0; q < 9; ++q) orow[q] = ci[tid][q];
        }
    }
}

// ---------------------------------------------------------------------------
// K3a: wh/wl = bf16 hi/lo split of [W1-W2 ; W2]
// ---------------------------------------------------------------------------
__global__ __launch_bounds__(256) void k3a_wcat(const float* __restrict__ cw,
                                               unsigned short* __restrict__ wh,
                                               unsigned short* __restrict__ wl) {
    const int i = blockIdx.x * 256 + threadIdx.x;
    if (i < 2 * OUTC * CC) {
        const int r = i / CC, c = i - r * CC;
        float val;
        if (r < OUTC) val = cw[r * (2 * CC) + c] - cw[r * (2 * CC) + CC + c];
        else          val = cw[(r - OUTC) * (2 * CC) + CC + c];
        const unsigned short h = f2bf(val);
        wh[i] = h;
        wl[i] = f2bf(val - bf2f(h));
    }
}

// ---------------------------------------------------------------------------
// K4_fused: one pass over the 9-neighbor gather:
//   amax[n][o] = u[n][o] + max_k v[idx][o],  amin = u + min_k v
//   per-block BN partials: S = sum_k (u+v), Q = sum_k (u+v)^2
// ---------------------------------------------------------------------------
__global__ __launch_bounds__(256) void k4_fused(const float* __restrict__ uv,
                                                const int* __restrict__ idxb,
                                                float* __restrict__ amax,
                                                float* __restrict__ amin,
                                                float* __restrict__ partials) {
    const int flat = blockIdx.x;
    const int b    = flat & 7;           // XCD pin
    const int tile = flat >> 3;
    const int tid  = threadIdx.x;
    const int p    = tid >> 3;
    const int g    = tid & 7;
    const int n    = tile * 32 + p;
    const size_t base = (size_t)b * NPTS;
    __shared__ float red[256 * 25];

    float sv[24], sv2[24], vmx[24], vmn[24];
#pragma unroll
    for (int c = 0; c < 24; ++c) { sv[c] = 0.f; sv2[c] = 0.f; vmx[c] = -3.4e38f; vmn[c] = 3.4e38f; }

    const int* ix = &idxb[(base + n) * KNN];
#pragma unroll
    for (int k = 0; k < KNN; ++k) {
        const int m = ix[k];
        const float* vr = &uv[(base + m) * (2 * OUTC) + OUTC + g * 24];
#pragma unroll
        for (int c4 = 0; c4 < 6; ++c4) {
            const float4 v = *(const float4*)&vr[c4 * 4];
            const int c = c4 * 4;
            sv[c+0] += v.x; sv2[c+0] += v.x*v.x; vmx[c+0] = fmaxf(vmx[c+0], v.x); vmn[c+0] = fminf(vmn[c+0], v.x);
            sv[c+1] += v.y; sv2[c+1] += v.y*v.y; vmx[c+1] = fmaxf(vmx[c+1], v.y); vmn[c+1] = fminf(vmn[c+1], v.y);
            sv[c+2] += v.z; sv2[c+2] += v.z*v.z; vmx[c+2] = fmaxf(vmx[c+2], v.z); vmn[c+2] = fminf(vmn[c+2], v.z);
            sv[c+3] += v.w; sv2[c+3] += v.w*v.w; vmx[c+3] = fmaxf(vmx[c+3], v.w); vmn[c+3] = fminf(vmn[c+3], v.w);
        }
    }
    const float* ur = &uv[(base + n) * (2 * OUTC) + g * 24];
    float S[24], Q[24];
    float* am = &amax[(base + n) * OUTC + g * 24];
    float* an = &amin[(base + n) * OUTC + g * 24];
#pragma unroll
    for (int c4 = 0; c4 < 6; ++c4) {
        const float4 u4 = *(const float4*)&ur[c4 * 4];
        const int c = c4 * 4;
        float4 mx, mn;
        mx.x = u4.x + vmx[c+0]; mn.x = u4.x + vmn[c+0];
        mx.y = u4.y + vmx[c+1]; mn.y = u4.y + vmn[c+1];
        mx.z = u4.z + vmx[c+2]; mn.z = u4.z + vmn[c+2];
        mx.w = u4.w + vmx[c+3]; mn.w = u4.w + vmn[c+3];
        *(float4*)&am[c4 * 4] = mx;
        *(float4*)&an[c4 * 4] = mn;
        S[c+0] = 9.f*u4.x + sv[c+0];  Q[c+0] = u4.x*(9.f*u4.x + 2.f*sv[c+0]) + sv2[c+0];
        S[c+1] = 9.f*u4.y + sv[c+1];  Q[c+1] = u4.y*(9.f*u4.y + 2.f*sv[c+1]) + sv2[c+1];
        S[c+2] = 9.f*u4.z + sv[c+2];  Q[c+2] = u4.z*(9.f*u4.z + 2.f*sv[c+2]) + sv2[c+2];
        S[c+3] = 9.f*u4.w + sv[c+3];  Q[c+3] = u4.w*(9.f*u4.w + 2.f*sv[c+3]) + sv2[c+3];
    }
#pragma unroll
    for (int c = 0; c < 24; ++c) red[tid * 25 + c] = S[c];
    __syncthreads();
    float accS = 0.f;
    if (tid < OUTC) {
        const int go = tid / 24, co = tid - go * 24;
        for (int pp = 0; pp < 32; ++pp) accS += red[(pp * 8 + go) * 25 + co];
    }
    __syncthreads();
#pragma unroll
    for (int c = 0; c < 24; ++c) red[tid * 25 + c] = Q[c];
    __syncthreads();
    if (tid < OUTC) {
        const int go = tid / 24, co = tid - go * 24;
        float accQ = 0.f;
        for (int pp = 0; pp < 32; ++pp) accQ += red[(pp * 8 + go) * 25 + co];
        partials[(size_t)flat * (2 * OUTC) + tid]        = accS;
        partials[(size_t)flat * (2 * OUTC) + OUTC + tid] = accQ;
    }
}

// ---------------------------------------------------------------------------
// K4b: parallel deterministic reduce: one block per channel.
// ---------------------------------------------------------------------------
__global__ __launch_bounds__(256) void k4b_finalize(const float* __restrict__ partials,
                                                    const float* __restrict__ gamma,
                                                    const float* __restrict__ beta,
                                                    float* __restrict__ scsh) {
    const int o   = blockIdx.x;
    const int tid = threadIdx.x;
    __shared__ float sS[256], sQ[256];
    float S = 0.f, Q = 0.f;
    for (int blk = tid; blk < NBLK4; blk += 256) {
        S += partials[(size_t)blk * (2 * OUTC) + o];
        Q += partials[(size_t)blk * (2 * OUTC) + OUTC + o];
    }
    sS[tid] = S; sQ[tid] = Q;
    __syncthreads();
    for (int s = 128; s > 0; s >>= 1) {
        if (tid < s) { sS[tid] += sS[tid + s]; sQ[tid] += sQ[tid + s]; }
        __syncthreads();
    }
    if (tid == 0) {
        const float cnt  = (float)BB * (float)NPTS * (float)KNN;
        const float mean = sS[0] / cnt;
        float var = fmaxf(sQ[0] / cnt - mean * mean, 0.0f);
        const float scale = gamma[o] * rsqrtf(var + 1e-5f);
        scsh[o]        = scale;
        scsh[OUTC + o] = beta[o] - mean * scale;
    }
}

// ---------------------------------------------------------------------------
// K5: out[b][o][n] = max(gelu(amax*sc+sh), gelu(amin*sc+sh))  (gelu unimodal)
// ---------------------------------------------------------------------------
__global__ __launch_bounds__(256) void k5_out(const float* __restrict__ amax,
                                              const float* __restrict__ amin,
                                              const float* __restrict__ scsh,
                                              float* __restrict__ out) {
    const int b  = blockIdx.y;
    const int n0 = blockIdx.x * 64;
    __shared__ float zb[64 * 193];
    __shared__ float ssc[OUTC];
    __shared__ float ssh[OUTC];
    const int tid = threadIdx.x;
    for (int q = tid; q < OUTC; q += 256) {
        ssc[q] = scsh[q];
        ssh[q] = scsh[OUTC + q];
    }
    __syncthreads();
    const int p  = tid >> 2;
    const int og = tid & 3;
    const int n  = n0 + p;
    const size_t rb = ((size_t)b * NPTS + n) * OUTC + og * 48;
#pragma unroll
    for (int t4 = 0; t4 < 12; ++t4) {
        const float4 ax = *(const float4*)&amax[rb + t4 * 4];
        const float4 an = *(const float4*)&amin[rb + t4 * 4];
        const int ob = og * 48 + t4 * 4;
        float z1, z2;
        z1 = ax.x * ssc[ob+0] + ssh[ob+0]; z2 = an.x * ssc[ob+0] + ssh[ob+0];
        zb[p * 193 + ob + 0] = fmaxf(gelu_f(z1), gelu_f(z2));
        z1 = ax.y * ssc[ob+1] + ssh[ob+1]; z2 = an.y * ssc[ob+1] + ssh[ob+1];
        zb[p * 193 + ob + 1] = fmaxf(gelu_f(z1), gelu_f(z2));
        z1 = ax.z * ssc[ob+2] + ssh[ob+2]; z2 = an.z * ssc[ob+2] + ssh[ob+2];
        zb[p * 193 + ob + 2] = fmaxf(gelu_f(z1), gelu_f(z2));
        z1 = ax.w * ssc[ob+3] + ssh[ob+3]; z2 = an.w * ssc[ob+3] + ssh[ob+3];
        zb[p * 193 + ob + 3] = fmaxf(gelu_f(z1), gelu_f(z2));
    }
    __syncthreads();
    float* ob2 = out + (size_t)b * OUTC * NPTS;
    for (int q = tid; q < 64 * OUTC; q += 256) {
        const int o  = q >> 6;
        const int pp = q & 63;
        ob2[(size_t)o * NPTS + n0 + pp] = zb[pp * 193 + o];
    }
}

// ---------------------------------------------------------------------------
extern "C" void kernel_launch(void* const* d_in, const int* in_sizes, int n_in,
                              void* d_out, int out_size, void* d_ws, size_t ws_size,
                              hipStream_t stream) {
    const float* x        = (const float*)d_in[0];
    const float* conv_w   = (const float*)d_in[1];
    const float* conv_b   = (const float*)d_in[2];
    const float* bn_gamma = (const float*)d_in[3];
    const float* bn_beta  = (const float*)d_in[4];
    float* out = (float*)d_out;

    // workspace layout
    float* ws = (float*)d_ws;
    const size_t SZ_XN = (size_t)BB * NPTS * CC;     // 4,816,896
    const size_t SZ_NV = (size_t)BB * NPTS;          // 25,088
    const size_t SZ_A  = (size_t)BB * NPTS * OUTC;   // 4,816,896

    int*   idxb        = (int*)ws;                                  // 225,792 i32
    unsigned short* wh = (unsigned short*)(idxb + (size_t)BB * NPTS * KNN);  // 73,728 u16
    unsigned short* wl = wh + (size_t)(2 * OUTC) * CC;                       // 73,728 u16
    float* uv       = (float*)(wl + (size_t)(2 * OUTC) * CC);       // 9,633,792 f
    float* partials = uv + (size_t)BB * NPTS * (2 * OUTC);          // NBLK4*384 f
    float* scsh     = partials + (size_t)NBLK4 * (2 * OUTC);        // 384 f
    float* normv    = scsh + 2 * OUTC;                              // 25,088 f
    float* sqv      = normv + SZ_NV;                                // 25,088 f
    float* xn       = sqv + SZ_NV;                                  // 4,816,896 f
    unsigned short* xh = (unsigned short*)(xn + SZ_XN);             // 4,816,896 u16
    unsigned short* xl = xh + SZ_XN;                                // 4,816,896 u16
    // pd DEDICATED (k3 writes uv concurrently in the mega dispatch):
    unsigned long long* pd = (unsigned long long*)(xl + SZ_XN);     // B*N*NCH*12 u64 = 4.8 MB
    // aliases (non-overlapping lifetimes):
    float* amax = xn;                                    // xn dead after k2b
    float* amin = xn + SZ_A;                             // spans dead xh/xl region

    k1_normalize<<<dim3(NTILES, BB), 256, 0, stream>>>(x, xn, xh, xl, normv, sqv);
    k3a_wcat<<<(2 * OUTC * CC + 255) / 256, 256, 0, stream>>>(conv_w, wh, wl);
    k23_mega<<<K2BLKS + K3BLKS, 256, 0, stream>>>(xh, xl, pd, wh, wl, normv, conv_b, uv);
    k2b_merge<<<dim3(BB, NT4), 128, 0, stream>>>(xn, sqv, pd, idxb);
    k4_fused<<<NBLK4, 256, 0, stream>>>(uv, idxb, amax, amin, partials);
    k4b_finalize<<<OUTC, 256, 0, stream>>>(partials, bn_gamma, bn_beta, scsh);
    k5_out<<<dim3(NTILES, BB), 256, 0, stream>>>(amax, amin, scsh, out);
}